// Round 10
// baseline (134.662 us; speedup 1.0000x reference)
//
#include <hip/hip_runtime.h>
#include <cstdint>
#include <cstddef>

// Problem constants
#define NIMG 32
#define C    128
#define OC   128
#define HW   112
#define HWSZ (HW * HW)       // 12544
#define NTAP 9
#define PHW  114             // padded spatial dim
#define XROW (PHW * C)       // 14592 B per padded LDS row
#define AWQ_BYTES ((size_t)4 * 9 * 4 * 64 * 16) // 147,456

typedef int v4i  __attribute__((ext_vector_type(4)));
typedef int v16i __attribute__((ext_vector_type(16)));

// ---------------------------------------------------------------------------
// Build A-fragments for mfma_i32_32x32x32_i8:
// awq[f][lane][16B], f = (wv*9 + tap)*4 + ks; lane l: row m = l&31,
// channel = ks*32 + (l>>5)*16 + byte.  A[m][k] = sign(w[wv*32+m][chan][tap]).
__global__ void pack_w_frag(const float* __restrict__ w, uint32_t* __restrict__ awq) {
    int tid = blockIdx.x * blockDim.x + threadIdx.x;   // 144 frags * 256 dwords
    int d = tid & 3, l = (tid >> 2) & 63, f = tid >> 8;
    int ks = f & 3, tf = f >> 2;
    int tap = tf % 9, wv = tf / 9;
    int o = wv * 32 + (l & 31);
    int cb = ks * 32 + ((l >> 5) & 1) * 16 + d * 4;
    uint32_t acc = 0;
    #pragma unroll
    for (int jj = 0; jj < 4; ++jj) {
        uint32_t bits = __float_as_uint(w[(size_t)(o * C + cb + jj) * NTAP + tap]);
        acc |= (((bits >> 31) * 0xFEu) ^ 1u) << (8 * jj);
    }
    awq[tid] = acc;
}

// ---------------------------------------------------------------------------
// Fused binary conv.  LDS layout per padded col (128B line): 16B slot
// (w + 4h) ^ (col&7) holds channels w*32 + h*16 + [0..15]  (w=chan-word 0..3,
// h=half 0..1).  With lane-fastest w in phase 1, every ds_write covers all 8
// bank-quads x 8 rows (conflict-free); phase-2 reads slot (ks+4h)^c7 -- also
// conflict-free.  MFMA accumulation split into two independent 18-deep chains.
__global__ __launch_bounds__(256, 2) void bconv_fused(const float* __restrict__ x,
                                                      const uint8_t* __restrict__ awq,
                                                      float* __restrict__ out) {
    __shared__ __align__(16) uint8_t sxq[4 * XROW];    // 58368 B: rows h0-1..h0+2
    int bid = blockIdx.x;                              // 1792 = 8 * 224, bijective
    int swz = (bid & 7) * 224 + (bid >> 3);
    int n = swz / 56, hp = swz % 56;
    int h0 = hp * 2;

    // ---- phase 1: load + sign-pack + conflict-free swizzled LDS stage ------
    #pragma unroll
    for (int rep = 0; rep < 2; ++rep) {
        int task = threadIdx.x + rep * 256;
        if (task < 448) {
            int r = task / 112, rem = task % 112;
            int w = rem & 3, pxg = rem >> 2;           // w lane-fastest!
            int hr = h0 - 1 + r;                       // image row
            int col0 = 1 + pxg * 4;
            int sbase = r * XROW;
            if (hr >= 0 && hr < HW) {
                const float* xp = x + ((size_t)(n * C + w * 32)) * HWSZ
                                    + (size_t)hr * HW + pxg * 4;
                uint32_t dw[4][8];
                #pragma unroll
                for (int j = 0; j < 4; ++j)
                    #pragma unroll
                    for (int d = 0; d < 8; ++d) dw[j][d] = 0u;
                #pragma unroll
                for (int c = 0; c < 32; ++c) {
                    float4 v = *reinterpret_cast<const float4*>(xp + (size_t)c * HWSZ);
                    uint32_t bm = 0xFFu << (8 * (c & 3));
                    int d = c >> 2;
                    dw[0][d] |= ((uint32_t)((int)__float_as_uint(v.x) >> 31)) & bm;
                    dw[1][d] |= ((uint32_t)((int)__float_as_uint(v.y) >> 31)) & bm;
                    dw[2][d] |= ((uint32_t)((int)__float_as_uint(v.z) >> 31)) & bm;
                    dw[3][d] |= ((uint32_t)((int)__float_as_uint(v.w) >> 31)) & bm;
                }
                #pragma unroll
                for (int j = 0; j < 4; ++j) {
                    int col = col0 + j;
                    int c7 = col & 7;
                    int line = sbase + col * 128;
                    uint32_t d0 = (dw[j][0] & 0xFEFEFEFEu) ^ 0x01010101u;
                    uint32_t d1 = (dw[j][1] & 0xFEFEFEFEu) ^ 0x01010101u;
                    uint32_t d2 = (dw[j][2] & 0xFEFEFEFEu) ^ 0x01010101u;
                    uint32_t d3 = (dw[j][3] & 0xFEFEFEFEu) ^ 0x01010101u;
                    *(uint4*)&sxq[line + (((w)     ^ c7) << 4)] = make_uint4(d0, d1, d2, d3);
                    uint32_t d4 = (dw[j][4] & 0xFEFEFEFEu) ^ 0x01010101u;
                    uint32_t d5 = (dw[j][5] & 0xFEFEFEFEu) ^ 0x01010101u;
                    uint32_t d6 = (dw[j][6] & 0xFEFEFEFEu) ^ 0x01010101u;
                    uint32_t d7 = (dw[j][7] & 0xFEFEFEFEu) ^ 0x01010101u;
                    *(uint4*)&sxq[line + (((w + 4) ^ c7) << 4)] = make_uint4(d4, d5, d6, d7);
                }
            } else {
                // image row out of range: zero-fill this task's LDS span
                #pragma unroll
                for (int j = 0; j < 4; ++j) {
                    int col = col0 + j;
                    int c7 = col & 7;
                    int line = sbase + col * 128;
                    *(uint4*)&sxq[line + (((w)     ^ c7) << 4)] = make_uint4(0u, 0u, 0u, 0u);
                    *(uint4*)&sxq[line + (((w + 4) ^ c7) << 4)] = make_uint4(0u, 0u, 0u, 0u);
                }
            }
        } else if (task < 456) {
            // pad columns 0 and 113 of each staged row (whole 128B line)
            int j = task - 448;
            int r = j >> 1, side = j & 1;
            int col = side ? 113 : 0;
            #pragma unroll
            for (int k = 0; k < 8; ++k)
                *(uint4*)&sxq[r * XROW + col * 128 + k * 16] = make_uint4(0u, 0u, 0u, 0u);
        }
    }

    // resident A fragments: 9 taps x 4 k-slices (144 VGPR/AGPR)
    int wv = threadIdx.x >> 6, l = threadIdx.x & 63;
    int l31 = l & 31, hh = l >> 5;
    v4i A[9][4];
    #pragma unroll
    for (int tap = 0; tap < 9; ++tap)
        #pragma unroll
        for (int ks = 0; ks < 4; ++ks) {
            int f = (wv * 9 + tap) * 4 + ks;
            A[tap][ks] = *(const v4i*)(awq + (size_t)f * 1024 + (size_t)l * 16);
        }
    __syncthreads();

    // ---- phase 2: 32x32x32 int8 MFMA over 7 N-tiles of 32 px ---------------
    float* outb = out + ((size_t)n * OC + wv * 32) * HWSZ + (size_t)h0 * HW;

    for (int nt = 0; nt < 7; ++nt) {
        int p = nt * 32 + l31;                         // px within the 2-row strip
        int rl = (p >= HW) ? 1 : 0;
        int w = p - rl * HW;

        int ad[3][4];
        #pragma unroll
        for (int kw = 0; kw < 3; ++kw) {
            int col = w + kw;                          // padded col, in-bounds
            int c7x = (col & 7) << 4;
            int b0 = rl * XROW + col * 128;
            #pragma unroll
            for (int ks = 0; ks < 4; ++ks)
                ad[kw][ks] = b0 + ((((ks + (hh << 2)) << 4)) ^ c7x);
        }

        v16i acc0 = {0,0,0,0,0,0,0,0,0,0,0,0,0,0,0,0};
        v16i acc1 = {0,0,0,0,0,0,0,0,0,0,0,0,0,0,0,0};
        #pragma unroll
        for (int kh = 0; kh < 3; ++kh)
            #pragma unroll
            for (int kw = 0; kw < 3; ++kw)
                #pragma unroll
                for (int ks = 0; ks < 4; ++ks) {
                    v4i b = *(const v4i*)&sxq[kh * XROW + ad[kw][ks]];
                    if (ks & 1)
                        acc1 = __builtin_amdgcn_mfma_i32_32x32x32_i8(
                                   A[kh * 3 + kw][ks], b, acc1, 0, 0, 0);
                    else
                        acc0 = __builtin_amdgcn_mfma_i32_32x32x32_i8(
                                   A[kh * 3 + kw][ks], b, acc0, 0, 0, 0);
                }
        v16i acc = acc0 + acc1;

        #pragma unroll
        for (int r = 0; r < 16; ++r) {
            int oof = (r & 3) + 8 * (r >> 2) + 4 * hh;         // D row (o)
            outb[(size_t)oof * HWSZ + rl * HW + w] = (float)acc[r];
        }
    }
}

// ===========================================================================
extern "C" void kernel_launch(void* const* d_in, const int* in_sizes, int n_in,
                              void* d_out, int out_size, void* d_ws, size_t ws_size,
                              hipStream_t stream) {
    const float* x   = (const float*)d_in[0];
    const float* wts = (const float*)d_in[1];
    float* out = (float*)d_out;
    uint32_t* awq = (uint32_t*)d_ws;

    hipLaunchKernelGGL(pack_w_frag, dim3(144), dim3(256), 0, stream, wts, awq);
    hipLaunchKernelGGL(bconv_fused, dim3(NIMG * 56), dim3(256), 0, stream,
                       x, (const uint8_t*)awq, out);
}